// Round 2
// baseline (583.285 us; speedup 1.0000x reference)
//
#include <hip/hip_runtime.h>
#include <hip/hip_bf16.h>

// Problem constants
#define BATCH 512
#define NN    200      // nodes per graph
#define INC   200
#define HID   256
#define OUTC  256
#define MTOT  (BATCH*NN)   // 102400 merged node rows

typedef __attribute__((ext_vector_type(8))) short bf16x8;
typedef __attribute__((ext_vector_type(4))) float f32x4;

__device__ __forceinline__ float bf2f(ushort u) {
    union { unsigned int i; float f; } v; v.i = ((unsigned int)u) << 16; return v.f;
}
__device__ __forceinline__ ushort f2bf(float f) {
    union { unsigned int i; float f; } v; v.f = f;
    unsigned int r = v.i + 0x7FFFu + ((v.i >> 16) & 1u);  // round-to-nearest-even
    return (ushort)(r >> 16);
}

// ---------------------------------------------------------------------------
// Detect input dtype. adj is exactly {0.0, 1.0}. If fp32: every even u16
// (low mantissa half, little-endian) is 0x0000. If bf16: even u16s are ~50%
// 0x3F80. flag = 1 -> bf16, 0 -> fp32.
__global__ void detect_dtype(const ushort* __restrict__ adj16, int* __restrict__ flag) {
    __shared__ int s;
    if (threadIdx.x == 0) s = 0;
    __syncthreads();
    if (adj16[2 * threadIdx.x] != 0) atomicOr(&s, 1);
    __syncthreads();
    if (threadIdx.x == 0) *flag = s;
}

// ---------------------------------------------------------------------------
// Prep: transpose W0 [200,256] -> W0t [256,200] bf16, W1 [256,256] -> W1t bf16
__global__ void prep_transpose(const void* __restrict__ W0,
                               const void* __restrict__ W1,
                               const int* __restrict__ flag,
                               ushort* __restrict__ W0t,
                               ushort* __restrict__ W1t) {
    const int f = *flag;
    int idx = blockIdx.x * 256 + threadIdx.x;
    if (idx < 200 * 256) {
        int k = idx >> 8, o = idx & 255;
        ushort v = f ? ((const ushort*)W0)[idx] : f2bf(((const float*)W0)[idx]);
        W0t[o * 200 + k] = v;
    }
    if (idx < 256 * 256) {
        int k = idx >> 8, o = idx & 255;
        ushort v = f ? ((const ushort*)W1)[idx] : f2bf(((const float*)W1)[idx]);
        W1t[o * 256 + k] = v;
    }
}

// Prep: Wp = W2 @ pw  -> [256][2] fp32, plus pb -> Wp[512..513]
__global__ void prep_wp(const void* __restrict__ W2,
                        const void* __restrict__ pw,
                        const void* __restrict__ pb,
                        const int* __restrict__ flag,
                        float* __restrict__ Wp) {
    const int f = *flag;
    int c = threadIdx.x;  // 0..255
    float s0 = 0.f, s1 = 0.f;
    for (int o = 0; o < 256; ++o) {
        float w  = f ? bf2f(((const ushort*)W2)[c * 256 + o]) : ((const float*)W2)[c * 256 + o];
        float p0 = f ? bf2f(((const ushort*)pw)[o * 2 + 0])   : ((const float*)pw)[o * 2 + 0];
        float p1 = f ? bf2f(((const ushort*)pw)[o * 2 + 1])   : ((const float*)pw)[o * 2 + 1];
        s0 += w * p0;
        s1 += w * p1;
    }
    Wp[c * 2 + 0] = s0;
    Wp[c * 2 + 1] = s1;
    if (c < 2) Wp[512 + c] = f ? bf2f(((const ushort*)pb)[c]) : ((const float*)pb)[c];
}

// Canonicalize features into bf16 [MTOT][INC]
__global__ void convert_feat(const void* __restrict__ feat,
                             const int* __restrict__ flag,
                             ushort* __restrict__ featB) {
    size_t i = ((size_t)blockIdx.x * 256 + threadIdx.x) * 8;
    if (i >= (size_t)MTOT * INC) return;
    if (*flag) {
        *(uint4*)(featB + i) = *(const uint4*)((const ushort*)feat + i);
    } else {
        const float* ff = (const float*)feat;
        ushort tmp[8];
#pragma unroll
        for (int j = 0; j < 8; j++) tmp[j] = f2bf(ff[i + j]);
        *(uint4*)(featB + i) = *(const uint4*)tmp;
    }
}

// ---------------------------------------------------------------------------
// M[b][n][m] = sigmoid(adj[b][n][m]) * (0.5*(R[n][m]+R[m][n]) + (n==m))
__global__ void compute_M(const void* __restrict__ adj,
                          const void* __restrict__ R,
                          const int* __restrict__ flag,
                          ushort* __restrict__ Mb) {
    int idx = blockIdx.x * 256 + threadIdx.x;
    if (idx >= BATCH * NN * NN) return;
    int nm = idx % (NN * NN);
    int n = nm / NN, m = nm % NN;
    const int f = *flag;
    float a, rn, rm;
    if (f) {
        a  = bf2f(((const ushort*)adj)[idx]);
        rn = bf2f(((const ushort*)R)[n * NN + m]);
        rm = bf2f(((const ushort*)R)[m * NN + n]);
    } else {
        a  = ((const float*)adj)[idx];
        rn = ((const float*)R)[n * NN + m];
        rm = ((const float*)R)[m * NN + n];
    }
    float s = 1.f / (1.f + __expf(-a));
    float mask = 0.5f * (rn + rm) + (n == m ? 1.f : 0.f);
    Mb[idx] = f2bf(s * mask);
}

// ---------------------------------------------------------------------------
// Tiled MFMA GEMM: C[M][Ntot] = A[M][K] * B[Ntot][K]^T   (both row-major, bf16)
// BM=BN=128, BK=32, 256 threads (4 waves, 2x2 wave grid, 4x4 16x16 frags/wave)
#define BM 128
#define BN 128
#define BK 32
#define LDSB 40  // padded LDS row stride in bf16 elems

__global__ __launch_bounds__(256, 2) void gemm_support(
    const ushort* __restrict__ A,    // [256][K] row-major (transposed weight)
    const ushort* __restrict__ Bt,   // [Ntot][K] row-major (= B^T)
    ushort* __restrict__ C,          // [256][Ntot] row-major
    int K, int lda, int ldb, int Ntot) {
    __shared__ __align__(16) ushort As[BM * LDSB];
    __shared__ __align__(16) ushort Bs[BN * LDSB];
    const int tid = threadIdx.x;
    const int mBase = blockIdx.y * BM;
    const int nBase = blockIdx.x * BN;
    const int c  = tid & 3;        // 16B chunk in row
    const int r0 = tid >> 2;       // 0..63
    const int wave = tid >> 6;
    const int lane = tid & 63;
    const int wm = (wave >> 1) * 64;
    const int wn = (wave & 1) * 64;
    const int fr = lane & 15;
    const int q  = lane >> 4;

    f32x4 acc[4][4];
#pragma unroll
    for (int i = 0; i < 4; i++)
#pragma unroll
        for (int j = 0; j < 4; j++) acc[i][j] = (f32x4){0.f, 0.f, 0.f, 0.f};

    const int nK = (K + BK - 1) / BK;
    for (int kk = 0; kk < nK; ++kk) {
        const int gk = kk * BK + c * 8;
        const bool kv = (gk < K);   // K % 8 == 0 so chunks are all-or-nothing
        uint4 z; z.x = z.y = z.z = z.w = 0u;
        uint4 a0 = kv ? *(const uint4*)(A  + (size_t)(mBase + r0)      * lda + gk) : z;
        uint4 a1 = kv ? *(const uint4*)(A  + (size_t)(mBase + r0 + 64) * lda + gk) : z;
        uint4 b0 = kv ? *(const uint4*)(Bt + (size_t)(nBase + r0)      * ldb + gk) : z;
        uint4 b1 = kv ? *(const uint4*)(Bt + (size_t)(nBase + r0 + 64) * ldb + gk) : z;
        *(uint4*)&As[r0 * LDSB + c * 8]        = a0;
        *(uint4*)&As[(r0 + 64) * LDSB + c * 8] = a1;
        *(uint4*)&Bs[r0 * LDSB + c * 8]        = b0;
        *(uint4*)&Bs[(r0 + 64) * LDSB + c * 8] = b1;
        __syncthreads();
        bf16x8 af[4], bf_[4];
#pragma unroll
        for (int i = 0; i < 4; i++) af[i]  = *(const bf16x8*)&As[(wm + i * 16 + fr) * LDSB + q * 8];
#pragma unroll
        for (int j = 0; j < 4; j++) bf_[j] = *(const bf16x8*)&Bs[(wn + j * 16 + fr) * LDSB + q * 8];
#pragma unroll
        for (int i = 0; i < 4; i++)
#pragma unroll
            for (int j = 0; j < 4; j++)
                acc[i][j] = __builtin_amdgcn_mfma_f32_16x16x32_bf16(af[i], bf_[j], acc[i][j], 0, 0, 0);
        __syncthreads();
    }
#pragma unroll
    for (int i = 0; i < 4; i++) {
        int row = mBase + wm + i * 16 + q * 4;
#pragma unroll
        for (int j = 0; j < 4; j++) {
            int col = nBase + wn + j * 16 + fr;
            f32x4 v = acc[i][j];
#pragma unroll
            for (int r = 0; r < 4; r++)
                C[(size_t)(row + r) * (size_t)Ntot + col] = f2bf(v[r]);
        }
    }
}

// Per-graph propagate: H[b][n][o] = sum_m M[b][n][m] * St[o][b*200+m]
// grid (nt=2, mt=2, b=512)
__global__ __launch_bounds__(256, 2) void gemm_prop(
    const ushort* __restrict__ Mb,   // [B][200][200]
    const ushort* __restrict__ St,   // [256][102400]
    ushort* __restrict__ H) {        // [B*200][256]
    const int b = blockIdx.z;
    const int mBase = blockIdx.y * BM;   // node rows (0 or 128)
    const int nBase = blockIdx.x * BN;   // channel cols (0 or 128)
    const ushort* A = Mb + (size_t)b * NN * NN;
    const int tid = threadIdx.x;
    const int c  = tid & 3;
    const int r0 = tid >> 2;
    const int wave = tid >> 6;
    const int lane = tid & 63;
    const int wm = (wave >> 1) * 64;
    const int wn = (wave & 1) * 64;
    const int fr = lane & 15;
    const int q  = lane >> 4;

    __shared__ __align__(16) ushort As[BM * LDSB];
    __shared__ __align__(16) ushort Bs[BN * LDSB];

    f32x4 acc[4][4];
#pragma unroll
    for (int i = 0; i < 4; i++)
#pragma unroll
        for (int j = 0; j < 4; j++) acc[i][j] = (f32x4){0.f, 0.f, 0.f, 0.f};

    const int nK = (NN + BK - 1) / BK;  // 7
    for (int kk = 0; kk < nK; ++kk) {
        const int gk = kk * BK + c * 8;
        const bool kv = (gk < NN);
        uint4 z; z.x = z.y = z.z = z.w = 0u;
        uint4 a0 = (kv && (mBase + r0)      < NN) ? *(const uint4*)(A + (size_t)(mBase + r0)      * NN + gk) : z;
        uint4 a1 = (kv && (mBase + r0 + 64) < NN) ? *(const uint4*)(A + (size_t)(mBase + r0 + 64) * NN + gk) : z;
        uint4 b0 = kv ? *(const uint4*)(St + (size_t)(nBase + r0)      * MTOT + (size_t)b * NN + gk) : z;
        uint4 b1 = kv ? *(const uint4*)(St + (size_t)(nBase + r0 + 64) * MTOT + (size_t)b * NN + gk) : z;
        *(uint4*)&As[r0 * LDSB + c * 8]        = a0;
        *(uint4*)&As[(r0 + 64) * LDSB + c * 8] = a1;
        *(uint4*)&Bs[r0 * LDSB + c * 8]        = b0;
        *(uint4*)&Bs[(r0 + 64) * LDSB + c * 8] = b1;
        __syncthreads();
        bf16x8 af[4], bf_[4];
#pragma unroll
        for (int i = 0; i < 4; i++) af[i]  = *(const bf16x8*)&As[(wm + i * 16 + fr) * LDSB + q * 8];
#pragma unroll
        for (int j = 0; j < 4; j++) bf_[j] = *(const bf16x8*)&Bs[(wn + j * 16 + fr) * LDSB + q * 8];
#pragma unroll
        for (int i = 0; i < 4; i++)
#pragma unroll
            for (int j = 0; j < 4; j++)
                acc[i][j] = __builtin_amdgcn_mfma_f32_16x16x32_bf16(af[i], bf_[j], acc[i][j], 0, 0, 0);
        __syncthreads();
    }
    ushort* Hb = H + (size_t)b * NN * HID;
#pragma unroll
    for (int i = 0; i < 4; i++) {
        int row = mBase + wm + i * 16 + q * 4;
#pragma unroll
        for (int j = 0; j < 4; j++) {
            int col = nBase + wn + j * 16 + fr;
            f32x4 v = acc[i][j];
#pragma unroll
            for (int r = 0; r < 4; r++)
                if (row + r < NN) Hb[(size_t)(row + r) * HID + col] = f2bf(v[r]);
        }
    }
}

// ---------------------------------------------------------------------------
// Final: u = colsum(M[b]); t[o] = sum_m u[m]*H2[b][m][o]; out = t@Wp/N + pb
__global__ __launch_bounds__(256) void finalize(
    const ushort* __restrict__ Mb, const ushort* __restrict__ H2,
    const float* __restrict__ Wp, const int* __restrict__ flag,
    void* __restrict__ outv) {
    const int b = blockIdx.x;
    const int tid = threadIdx.x;
    __shared__ float u[NN];
    const ushort* M = Mb + (size_t)b * NN * NN;
    if (tid < NN) {
        float s = 0.f;
        for (int n = 0; n < NN; ++n) s += bf2f(M[n * NN + tid]);
        u[tid] = s;
    }
    __syncthreads();
    const ushort* H = H2 + (size_t)b * NN * HID;
    float t = 0.f;
    for (int m = 0; m < NN; ++m) t += u[m] * bf2f(H[m * HID + tid]);
    float p0 = t * Wp[tid * 2 + 0];
    float p1 = t * Wp[tid * 2 + 1];
#pragma unroll
    for (int off = 32; off > 0; off >>= 1) {
        p0 += __shfl_down(p0, off);
        p1 += __shfl_down(p1, off);
    }
    __shared__ float w0s[4], w1s[4];
    int wave = tid >> 6, lane = tid & 63;
    if (lane == 0) { w0s[wave] = p0; w1s[wave] = p1; }
    __syncthreads();
    if (tid == 0) {
        float a0 = w0s[0] + w0s[1] + w0s[2] + w0s[3];
        float a1 = w1s[0] + w1s[1] + w1s[2] + w1s[3];
        float o0 = a0 * (1.f / NN) + Wp[512];
        float o1 = a1 * (1.f / NN) + Wp[513];
        if (*flag) {
            ((ushort*)outv)[b * 2 + 0] = f2bf(o0);
            ((ushort*)outv)[b * 2 + 1] = f2bf(o1);
        } else {
            ((float*)outv)[b * 2 + 0] = o0;
            ((float*)outv)[b * 2 + 1] = o1;
        }
    }
}

// ---------------------------------------------------------------------------
extern "C" void kernel_launch(void* const* d_in, const int* in_sizes, int n_in,
                              void* d_out, int out_size, void* d_ws, size_t ws_size,
                              hipStream_t stream) {
    const void* adj  = d_in[0];
    const void* feat = d_in[1];
    const void* R    = d_in[2];
    const void* W0   = d_in[3];
    const void* W1   = d_in[4];
    const void* W2   = d_in[5];
    const void* pw   = d_in[6];
    const void* pb   = d_in[7];

    char* ws = (char*)d_ws;
    // layout (bytes):
    //   flag @ 0
    //   Wp   @ 1024   (514 floats: 256x2 Wp + pb[2])
    //   W0t  @ 4096        (102,400 B)
    //   W1t  @ 106,496     (131,072 B)
    //   Mb   @ 237,568     (40,960,000 B)
    //   St   @ 41,197,568  (52,428,800 B)
    //   H    @ 93,626,368  (52,428,800 B)  -- also aliased as featB
    int*    flag = (int*)(ws);
    float*  Wp   = (float*)(ws + 1024);
    ushort* W0t  = (ushort*)(ws + 4096);
    ushort* W1t  = (ushort*)(ws + 106496);
    ushort* Mb   = (ushort*)(ws + 237568);
    ushort* St   = (ushort*)(ws + 41197568);
    ushort* H    = (ushort*)(ws + 93626368);
    ushort* featB = H;   // featB dead after S0 GEMM; H first written after that

    detect_dtype<<<1, 256, 0, stream>>>((const ushort*)adj, flag);
    prep_transpose<<<256, 256, 0, stream>>>(W0, W1, flag, W0t, W1t);
    prep_wp<<<1, 256, 0, stream>>>(W2, pw, pb, flag, Wp);
    convert_feat<<<(MTOT * INC / 8 + 255) / 256, 256, 0, stream>>>(feat, flag, featB);
    compute_M<<<(BATCH * NN * NN + 255) / 256, 256, 0, stream>>>(adj, R, flag, Mb);

    // S0^T = W0t @ feat^T : [256x200]·[200x102400]
    gemm_support<<<dim3(MTOT / BN, 2), 256, 0, stream>>>(W0t, featB, St, INC, INC, INC, MTOT);
    // H1 = M @ S0   (overwrites featB region -- featB consumed above)
    gemm_prop<<<dim3(2, 2, BATCH), 256, 0, stream>>>(Mb, St, H);
    // S1^T = W1t @ H1^T : [256x256]·[256x102400]
    gemm_support<<<dim3(MTOT / BN, 2), 256, 0, stream>>>(W1t, H, St, HID, HID, HID, MTOT);
    // H2 = M @ S1
    gemm_prop<<<dim3(2, 2, BATCH), 256, 0, stream>>>(Mb, St, H);
    // out = (u^T H2) @ (W2 pw) / N + pb
    finalize<<<BATCH, 256, 0, stream>>>(Mb, H, Wp, flag, d_out);
}

// Round 3
// 421.690 us; speedup vs baseline: 1.3832x; 1.3832x over previous
//
#include <hip/hip_runtime.h>

// Problem constants
#define BATCH 512
#define NN    200
#define INC   200
#define HID   256
#define MTOT  (BATCH*NN)     // 102400
#define KP    224            // K padded to multiple of 32
#define GSTR  (NN*KP)        // Mb per-graph elems (200x224 = 44800)

typedef __attribute__((ext_vector_type(8))) short bf16x8;
typedef __attribute__((ext_vector_type(4))) float f32x4;

__device__ __forceinline__ float bf2f(ushort u) {
    union { unsigned int i; float f; } v; v.i = ((unsigned int)u) << 16; return v.f;
}
__device__ __forceinline__ ushort f2bf(float f) {
    union { unsigned int i; float f; } v; v.f = f;
    unsigned int r = v.i + 0x7FFFu + ((v.i >> 16) & 1u);  // RNE
    return (ushort)(r >> 16);
}

// async global->LDS, 16B per lane; lds dest is wave-uniform base + lane*16
__device__ __forceinline__ void gl_lds16(const void* g, void* l) {
    __builtin_amdgcn_global_load_lds(
        (const __attribute__((address_space(1))) unsigned int*)g,
        (__attribute__((address_space(3))) unsigned int*)l, 16, 0, 0);
}

// ---------------------------------------------------------------------------
// W0 [200,256] -> W0t [256,224] (K-padded), W1 [256,256] -> W1t [256,256]
__global__ void prep_transpose(const float* __restrict__ W0,
                               const float* __restrict__ W1,
                               ushort* __restrict__ W0t,
                               ushort* __restrict__ W1t) {
    int idx = blockIdx.x * 256 + threadIdx.x;   // up to 65536
    if (idx < 256 * KP) {
        int o = idx / KP, k = idx % KP;
        W0t[idx] = (k < 200) ? f2bf(W0[k * 256 + o]) : (ushort)0;
    }
    if (idx < 256 * 256) {
        int o = idx >> 8, k = idx & 255;
        W1t[o * 256 + k] = f2bf(W1[k * 256 + o]);
    }
}

// Wp = W2 @ pw -> [256][2] fp32; pb -> Wp[512..513]
__global__ void prep_wp(const float* __restrict__ W2,
                        const float* __restrict__ pw,
                        const float* __restrict__ pb,
                        float* __restrict__ Wp) {
    int c = threadIdx.x;
    float s0 = 0.f, s1 = 0.f;
    for (int o = 0; o < 256; ++o) {
        float w = W2[c * 256 + o];
        s0 += w * pw[o * 2 + 0];
        s1 += w * pw[o * 2 + 1];
    }
    Wp[c * 2 + 0] = s0;
    Wp[c * 2 + 1] = s1;
    if (c < 2) Wp[512 + c] = pb[c];
}

// Rs[n][m] = 0.5*(R[n][m]+R[m][n]) + (n==m), bf16, [200][224] zero-padded
__global__ void prep_mask(const float* __restrict__ R, ushort* __restrict__ Rs) {
    int idx = blockIdx.x * 256 + threadIdx.x;
    if (idx >= NN * KP) return;
    int n = idx / KP, m = idx % KP;
    float v = 0.f;
    if (m < NN) v = 0.5f * (R[n * NN + m] + R[m * NN + n]) + (n == m ? 1.f : 0.f);
    Rs[idx] = f2bf(v);
}

// features fp32 [102400][200] -> bf16 [102400][224] zero-padded
__global__ void convert_feat(const float* __restrict__ feat, ushort* __restrict__ featB) {
    int c = blockIdx.x * 256 + threadIdx.x;     // MTOT*28 chunks of 8
    if (c >= MTOT * 28) return;
    int row = c / 28, cc = c % 28, m0 = cc * 8;
    __align__(16) ushort tmp[8];
    if (m0 < 200) {
        const float* src = feat + (size_t)row * INC + m0;
#pragma unroll
        for (int j = 0; j < 8; j++) tmp[j] = f2bf(src[j]);
    } else {
#pragma unroll
        for (int j = 0; j < 8; j++) tmp[j] = 0;
    }
    *(uint4*)(featB + (size_t)row * KP + m0) = *(const uint4*)tmp;
}

// M[b][n][m] = sigmoid(adj)*Rs[n][m], bf16 [B][200][224] zero-padded cols
__global__ void compute_M(const float* __restrict__ adj,
                          const ushort* __restrict__ Rs,
                          ushort* __restrict__ Mb) {
    int c = blockIdx.x * 256 + threadIdx.x;     // BATCH*200*28
    if (c >= BATCH * 5600) return;
    int b = c / 5600, r = c % 5600;
    int n = r / 28, mc = r % 28, m0 = mc * 8;
    __align__(16) ushort tmp[8];
    if (m0 < NN) {
        const float* src = adj + ((size_t)(b * NN + n)) * NN + m0;
        const ushort* rsp = Rs + n * KP + m0;
#pragma unroll
        for (int j = 0; j < 8; j++) {
            float a = src[j];
            float s = 1.f / (1.f + __expf(-a));
            tmp[j] = f2bf(s * bf2f(rsp[j]));
        }
    } else {
#pragma unroll
        for (int j = 0; j < 8; j++) tmp[j] = 0;
    }
    *(uint4*)(Mb + (size_t)b * GSTR + n * KP + m0) = *(const uint4*)tmp;
}

// ---------------------------------------------------------------------------
// C[M][Ntot] = A[M][K] * B[Ntot][K]^T, bf16, K % 32 == 0, global_load_lds staging
__global__ __launch_bounds__(256, 2) void gemm_support(
    const ushort* __restrict__ A, const ushort* __restrict__ Bt,
    ushort* __restrict__ C, int K, int lda, int ldb, int Ntot) {
    __shared__ __align__(16) ushort As[128 * 32];
    __shared__ __align__(16) ushort Bs[128 * 32];
    const int tid = threadIdx.x;
    const int mBase = blockIdx.y * 128, nBase = blockIdx.x * 128;
    const int wave = tid >> 6, lane = tid & 63;
    const int srow = wave * 16 + (lane >> 2);
    const int scol = (lane & 3) * 8;
    const ushort* gA0 = A + (size_t)(mBase + srow) * lda + scol;
    const ushort* gA1 = gA0 + (size_t)64 * lda;
    const ushort* gB0 = Bt + (size_t)(nBase + srow) * ldb + scol;
    const ushort* gB1 = gB0 + (size_t)64 * ldb;
    ushort* lA0 = &As[wave * 512];
    ushort* lA1 = &As[2048 + wave * 512];
    ushort* lB0 = &Bs[wave * 512];
    ushort* lB1 = &Bs[2048 + wave * 512];
    const int wm = (wave >> 1) * 64, wn = (wave & 1) * 64;
    const int fr = lane & 15, q = lane >> 4;

    f32x4 acc[4][4];
#pragma unroll
    for (int i = 0; i < 4; i++)
#pragma unroll
        for (int j = 0; j < 4; j++) acc[i][j] = (f32x4){0.f, 0.f, 0.f, 0.f};

    const int nK = K / 32;
    for (int kk = 0; kk < nK; ++kk) {
        const int ko = kk * 32;
        __syncthreads();
        gl_lds16(gA0 + ko, lA0);
        gl_lds16(gA1 + ko, lA1);
        gl_lds16(gB0 + ko, lB0);
        gl_lds16(gB1 + ko, lB1);
        __syncthreads();
        bf16x8 af[4], bfr[4];
#pragma unroll
        for (int i = 0; i < 4; i++) af[i]  = *(const bf16x8*)&As[(wm + i * 16 + fr) * 32 + q * 8];
#pragma unroll
        for (int j = 0; j < 4; j++) bfr[j] = *(const bf16x8*)&Bs[(wn + j * 16 + fr) * 32 + q * 8];
#pragma unroll
        for (int i = 0; i < 4; i++)
#pragma unroll
            for (int j = 0; j < 4; j++)
                acc[i][j] = __builtin_amdgcn_mfma_f32_16x16x32_bf16(af[i], bfr[j], acc[i][j], 0, 0, 0);
    }
#pragma unroll
    for (int i = 0; i < 4; i++) {
        int row = mBase + wm + i * 16 + q * 4;
#pragma unroll
        for (int j = 0; j < 4; j++) {
            int col = nBase + wn + j * 16 + fr;
            f32x4 v = acc[i][j];
#pragma unroll
            for (int r = 0; r < 4; r++)
                C[(size_t)(row + r) * (size_t)Ntot + col] = f2bf(v[r]);
        }
    }
}

// H[b][n][o] = sum_m M[b][n][m] * St[o][b*200+m]; K = KP (A col-pad zeros)
__global__ __launch_bounds__(256, 2) void gemm_prop(
    const ushort* __restrict__ Mb, const ushort* __restrict__ St,
    ushort* __restrict__ H) {
    __shared__ __align__(16) ushort As[128 * 32];
    __shared__ __align__(16) ushort Bs[128 * 32];
    const int b = blockIdx.z;
    const int mBase = blockIdx.y * 128, nBase = blockIdx.x * 128;
    const ushort* A = Mb + (size_t)b * GSTR;
    const int tid = threadIdx.x;
    const int wave = tid >> 6, lane = tid & 63;
    const int srow = wave * 16 + (lane >> 2);
    const int scol = (lane & 3) * 8;
    const ushort* gA0 = A + (size_t)(mBase + srow) * KP + scol;   // rows>=200 garbage->discarded
    const ushort* gA1 = gA0 + (size_t)64 * KP;
    const ushort* gB0 = St + (size_t)(nBase + srow) * MTOT + b * NN + scol;
    const ushort* gB1 = gB0 + (size_t)64 * MTOT;
    ushort* lA0 = &As[wave * 512];
    ushort* lA1 = &As[2048 + wave * 512];
    ushort* lB0 = &Bs[wave * 512];
    ushort* lB1 = &Bs[2048 + wave * 512];
    const int wm = (wave >> 1) * 64, wn = (wave & 1) * 64;
    const int fr = lane & 15, q = lane >> 4;

    f32x4 acc[4][4];
#pragma unroll
    for (int i = 0; i < 4; i++)
#pragma unroll
        for (int j = 0; j < 4; j++) acc[i][j] = (f32x4){0.f, 0.f, 0.f, 0.f};

    const int nK = KP / 32;   // 7
    for (int kk = 0; kk < nK; ++kk) {
        const int ko = kk * 32;
        __syncthreads();
        gl_lds16(gA0 + ko, lA0);
        gl_lds16(gA1 + ko, lA1);
        gl_lds16(gB0 + ko, lB0);
        gl_lds16(gB1 + ko, lB1);
        __syncthreads();
        bf16x8 af[4], bfr[4];
#pragma unroll
        for (int i = 0; i < 4; i++) af[i]  = *(const bf16x8*)&As[(wm + i * 16 + fr) * 32 + q * 8];
#pragma unroll
        for (int j = 0; j < 4; j++) bfr[j] = *(const bf16x8*)&Bs[(wn + j * 16 + fr) * 32 + q * 8];
#pragma unroll
        for (int i = 0; i < 4; i++)
#pragma unroll
            for (int j = 0; j < 4; j++)
                acc[i][j] = __builtin_amdgcn_mfma_f32_16x16x32_bf16(af[i], bfr[j], acc[i][j], 0, 0, 0);
    }
    ushort* Hb = H + (size_t)b * NN * HID;
#pragma unroll
    for (int i = 0; i < 4; i++) {
        int row = mBase + wm + i * 16 + q * 4;
#pragma unroll
        for (int j = 0; j < 4; j++) {
            int col = nBase + wn + j * 16 + fr;
            f32x4 v = acc[i][j];
#pragma unroll
            for (int r = 0; r < 4; r++)
                if (row + r < NN) Hb[(size_t)(row + r) * HID + col] = f2bf(v[r]);
        }
    }
}

// ---------------------------------------------------------------------------
// u = colsum(M[b]); t[o] = sum_m u[m]*H2[b][m][o]; out = t@Wp/N + pb (fp32 out)
__global__ __launch_bounds__(256) void finalize(
    const ushort* __restrict__ Mb, const ushort* __restrict__ H2,
    const float* __restrict__ Wp, float* __restrict__ out) {
    const int b = blockIdx.x;
    const int tid = threadIdx.x;
    __shared__ float u[NN];
    const ushort* M = Mb + (size_t)b * GSTR;
    if (tid < NN) {
        float s = 0.f;
        for (int n = 0; n < NN; ++n) s += bf2f(M[n * KP + tid]);
        u[tid] = s;
    }
    __syncthreads();
    const ushort* Hh = H2 + (size_t)b * NN * HID;
    float t = 0.f;
    for (int m = 0; m < NN; ++m) t += u[m] * bf2f(Hh[m * HID + tid]);
    float p0 = t * Wp[tid * 2 + 0];
    float p1 = t * Wp[tid * 2 + 1];
#pragma unroll
    for (int off = 32; off > 0; off >>= 1) {
        p0 += __shfl_down(p0, off);
        p1 += __shfl_down(p1, off);
    }
    __shared__ float w0s[4], w1s[4];
    int wave = tid >> 6, lane = tid & 63;
    if (lane == 0) { w0s[wave] = p0; w1s[wave] = p1; }
    __syncthreads();
    if (tid == 0) {
        float a0 = w0s[0] + w0s[1] + w0s[2] + w0s[3];
        float a1 = w1s[0] + w1s[1] + w1s[2] + w1s[3];
        out[b * 2 + 0] = a0 * (1.f / NN) + Wp[512];
        out[b * 2 + 1] = a1 * (1.f / NN) + Wp[513];
    }
}

// ---------------------------------------------------------------------------
extern "C" void kernel_launch(void* const* d_in, const int* in_sizes, int n_in,
                              void* d_out, int out_size, void* d_ws, size_t ws_size,
                              hipStream_t stream) {
    const float* adj  = (const float*)d_in[0];
    const float* feat = (const float*)d_in[1];
    const float* R    = (const float*)d_in[2];
    const float* W0   = (const float*)d_in[3];
    const float* W1   = (const float*)d_in[4];
    const float* W2   = (const float*)d_in[5];
    const float* pw   = (const float*)d_in[6];
    const float* pb   = (const float*)d_in[7];

    char* ws = (char*)d_ws;
    // layout (bytes):
    float*  Wp   = (float*)(ws);                 // 2056 B (pad to 4096)
    ushort* W0t  = (ushort*)(ws + 4096);         // 114,688
    ushort* W1t  = (ushort*)(ws + 118784);       // 131,072
    ushort* Rs   = (ushort*)(ws + 249856);       // 89,600 (pad to 339,968)
    ushort* Mb   = (ushort*)(ws + 339968);       // 45,875,200
    ushort* St   = (ushort*)(ws + 46215168);     // 52,428,800
    ushort* H    = (ushort*)(ws + 98643968);     // 52,428,800 (featB aliased)
    ushort* featB = H;                           // dead after S0 GEMM

    prep_transpose<<<256, 256, 0, stream>>>(W0, W1, W0t, W1t);
    prep_wp<<<1, 256, 0, stream>>>(W2, pw, pb, Wp);
    prep_mask<<<(NN * KP + 255) / 256, 256, 0, stream>>>(R, Rs);
    convert_feat<<<(MTOT * 28 + 255) / 256, 256, 0, stream>>>(feat, featB);
    compute_M<<<(BATCH * 5600 + 255) / 256, 256, 0, stream>>>(adj, Rs, Mb);

    // S0^T = W0t @ feat^T : [256x224]·[224x102400]
    gemm_support<<<dim3(MTOT / 128, 2), 256, 0, stream>>>(W0t, featB, St, KP, KP, KP, MTOT);
    // H1 = M @ S0
    gemm_prop<<<dim3(2, 2, BATCH), 256, 0, stream>>>(Mb, St, H);
    // S1^T = W1t @ H1^T : [256x256]·[256x102400]
    gemm_support<<<dim3(MTOT / 128, 2), 256, 0, stream>>>(W1t, H, St, HID, HID, HID, MTOT);
    // H2 = M @ S1
    gemm_prop<<<dim3(2, 2, BATCH), 256, 0, stream>>>(Mb, St, H);
    // out = (u^T H2) @ (W2 pw) / N + pb
    finalize<<<BATCH, 256, 0, stream>>>(Mb, H, Wp, (float*)d_out);
}

// Round 4
// 374.819 us; speedup vs baseline: 1.5562x; 1.1250x over previous
//
#include <hip/hip_runtime.h>

// Problem constants
#define BATCH 512
#define NN    200
#define INC   200
#define HID   256
#define MTOT  (BATCH*NN)     // 102400
#define KP    224            // K padded to multiple of 32
#define GSTR  (NN*KP)        // 44800: per-graph elems of Mb and featB
#define SSTR  (HID*NN)       // 51200: per-graph elems of St [256][200]
#define HSTR  (NN*HID)       // 51200: per-graph elems of H  [200][256]

typedef __attribute__((ext_vector_type(8))) short bf16x8;
typedef __attribute__((ext_vector_type(4))) float f32x4;

__device__ __forceinline__ float bf2f(ushort u) {
    union { unsigned int i; float f; } v; v.i = ((unsigned int)u) << 16; return v.f;
}
__device__ __forceinline__ ushort f2bf(float f) {
    union { unsigned int i; float f; } v; v.f = f;
    unsigned int r = v.i + 0x7FFFu + ((v.i >> 16) & 1u);  // RNE
    return (ushort)(r >> 16);
}

// async global->LDS, 16B/lane; LDS dest = wave-uniform base + lane*16
__device__ __forceinline__ void gl_lds16(const void* g, void* l) {
    __builtin_amdgcn_global_load_lds(
        (const __attribute__((address_space(1))) unsigned int*)g,
        (__attribute__((address_space(3))) unsigned int*)l, 16, 0, 0);
}

// ---------------------------------------------------------------------------
// W0 [200,256] -> W0t [256,224] (K-pad zeros), W1 [256,256] -> W1t [256,256]
__global__ void prep_transpose(const float* __restrict__ W0,
                               const float* __restrict__ W1,
                               ushort* __restrict__ W0t,
                               ushort* __restrict__ W1t) {
    int idx = blockIdx.x * 256 + threadIdx.x;
    if (idx < 256 * KP) {
        int o = idx / KP, k = idx % KP;
        W0t[idx] = (k < 200) ? f2bf(W0[k * 256 + o]) : (ushort)0;
    }
    if (idx < 256 * 256) {
        int o = idx >> 8, k = idx & 255;
        W1t[o * 256 + k] = f2bf(W1[k * 256 + o]);
    }
}

// Wp = W2 @ pw -> [256][2] fp32; pb -> Wp[512..513]
__global__ void prep_wp(const float* __restrict__ W2,
                        const float* __restrict__ pw,
                        const float* __restrict__ pb,
                        float* __restrict__ Wp) {
    int c = threadIdx.x;
    float s0 = 0.f, s1 = 0.f;
    for (int o = 0; o < 256; ++o) {
        float w = W2[c * 256 + o];
        s0 += w * pw[o * 2 + 0];
        s1 += w * pw[o * 2 + 1];
    }
    Wp[c * 2 + 0] = s0;
    Wp[c * 2 + 1] = s1;
    if (c < 2) Wp[512 + c] = pb[c];
}

// Rs[n][m] = 0.5*(R[n][m]+R[m][n]) + (n==m), bf16 [200][224] zero-padded
__global__ void prep_mask(const float* __restrict__ R, ushort* __restrict__ Rs) {
    int idx = blockIdx.x * 256 + threadIdx.x;
    if (idx >= NN * KP) return;
    int n = idx / KP, m = idx % KP;
    float v = 0.f;
    if (m < NN) v = 0.5f * (R[n * NN + m] + R[m * NN + n]) + (n == m ? 1.f : 0.f);
    Rs[idx] = f2bf(v);
}

// features fp32 [102400][200] -> bf16 [102400][224] (zero K-pad)
__global__ void convert_feat(const float* __restrict__ feat, ushort* __restrict__ featB) {
    int c = blockIdx.x * 256 + threadIdx.x;     // MTOT*28 chunks of 8
    if (c >= MTOT * 28) return;
    int row = c / 28, cc = c % 28, m0 = cc * 8;
    __align__(16) ushort tmp[8];
    if (m0 < 200) {
        const float* src = feat + (size_t)row * INC + m0;
#pragma unroll
        for (int j = 0; j < 8; j++) tmp[j] = f2bf(src[j]);
    } else {
#pragma unroll
        for (int j = 0; j < 8; j++) tmp[j] = 0;
    }
    *(uint4*)(featB + (size_t)row * KP + m0) = *(const uint4*)tmp;
}

// M[b][n][m] = sigmoid(adj)*Rs[n][m], bf16 [512][200][224] (zero K-pad)
__global__ void compute_M(const float* __restrict__ adj,
                          const ushort* __restrict__ Rs,
                          ushort* __restrict__ Mb) {
    int c = blockIdx.x * 256 + threadIdx.x;     // BATCH*200*28
    if (c >= BATCH * 5600) return;
    int b = c / 5600, r = c % 5600;
    int n = r / 28, mc = r % 28, m0 = mc * 8;
    __align__(16) ushort tmp[8];
    if (m0 < NN) {
        const float* src = adj + ((size_t)(b * NN + n)) * NN + m0;
        const ushort* rsp = Rs + n * KP + m0;
#pragma unroll
        for (int j = 0; j < 8; j++) {
            float a = src[j];
            float s = 1.f / (1.f + __expf(-a));
            tmp[j] = f2bf(s * bf2f(rsp[j]));
        }
    } else {
#pragma unroll
        for (int j = 0; j < 8; j++) tmp[j] = 0;
    }
    *(uint4*)(Mb + (size_t)b * GSTR + n * KP + m0) = *(const uint4*)tmp;
}

// ---------------------------------------------------------------------------
// Support GEMM: S^T[b][o][m] = sum_k W^T[o][k] * X[b][m][k]
// BM=256 (all channels, one block), BN=128 nodes, 4 waves, 4x8 frags/wave.
// grid: 1024 blocks; block x -> b = x>>1, node0 = (x&1)*128.
__global__ __launch_bounds__(256, 2) void gemm_sup(
    const ushort* __restrict__ A,    // weights^T [256][K], lda=K
    const ushort* __restrict__ Bt,   // X [512][NN][ldb] graph rows, node-major
    ushort* __restrict__ St,         // [512][256][200]
    int K, int gstride, int ldb) {
    __shared__ __align__(16) ushort As[256 * 32];
    __shared__ __align__(16) ushort Bs[128 * 32];
    const int tid = threadIdx.x;
    const int b = blockIdx.x >> 1;
    const int node0 = (blockIdx.x & 1) * 128;
    const int w = tid >> 6, ln = tid & 63;
    const int sr = ln >> 2, sc = (ln & 3) * 8;
    const int fr = ln & 15, q = ln >> 4;

    const ushort* gA[4];
#pragma unroll
    for (int t = 0; t < 4; t++)
        gA[t] = A + (size_t)(t * 64 + w * 16 + sr) * K + sc;
    const ushort* gB[2];
#pragma unroll
    for (int t = 0; t < 2; t++) {
        int node = node0 + t * 64 + w * 16 + sr;
        if (node > NN - 1) node = NN - 1;   // clamp: garbage rows -> discarded cols
        gB[t] = Bt + (size_t)b * gstride + (size_t)node * ldb + sc;
    }
    ushort* lA[4];
#pragma unroll
    for (int t = 0; t < 4; t++) lA[t] = &As[(t * 64 + w * 16) * 32];
    ushort* lB[2];
#pragma unroll
    for (int t = 0; t < 2; t++) lB[t] = &Bs[(t * 64 + w * 16) * 32];

    f32x4 acc[4][8];
#pragma unroll
    for (int i = 0; i < 4; i++)
#pragma unroll
        for (int j = 0; j < 8; j++) acc[i][j] = (f32x4){0.f, 0.f, 0.f, 0.f};

    const int nK = K / 32;
    for (int kk = 0; kk < nK; ++kk) {
        const int ko = kk * 32;
        __syncthreads();
#pragma unroll
        for (int t = 0; t < 4; t++) gl_lds16(gA[t] + ko, lA[t]);
#pragma unroll
        for (int t = 0; t < 2; t++) gl_lds16(gB[t] + ko, lB[t]);
        __syncthreads();
        bf16x8 af[4], bfr[8];
#pragma unroll
        for (int i = 0; i < 4; i++) af[i]  = *(const bf16x8*)&As[(w * 64 + i * 16 + fr) * 32 + q * 8];
#pragma unroll
        for (int j = 0; j < 8; j++) bfr[j] = *(const bf16x8*)&Bs[(j * 16 + fr) * 32 + q * 8];
#pragma unroll
        for (int i = 0; i < 4; i++)
#pragma unroll
            for (int j = 0; j < 8; j++)
                acc[i][j] = __builtin_amdgcn_mfma_f32_16x16x32_bf16(af[i], bfr[j], acc[i][j], 0, 0, 0);
    }
    ushort* Sb = St + (size_t)b * SSTR;
#pragma unroll
    for (int i = 0; i < 4; i++) {
        int o = w * 64 + i * 16 + q * 4;
#pragma unroll
        for (int j = 0; j < 8; j++) {
            int m = node0 + j * 16 + fr;
            if (m < NN) {
                f32x4 v = acc[i][j];
#pragma unroll
                for (int r = 0; r < 4; r++)
                    Sb[(o + r) * NN + m] = f2bf(v[r]);
            }
        }
    }
}

// Propagate GEMM: H[b][n][o] = sum_m M[b][n][m] * St[b][o][m]
// BM=256 (all M rows; >=200 garbage-discarded), BN=128 channels. grid (2,512).
__global__ __launch_bounds__(256, 2) void gemm_prop(
    const ushort* __restrict__ Mb,   // [512][200][224], K-pad zeros
    const ushort* __restrict__ St,   // [512][256][200]
    ushort* __restrict__ H) {        // [512][200][256]
    __shared__ __align__(16) ushort As[256 * 32];
    __shared__ __align__(16) ushort Bs[128 * 32];
    const int tid = threadIdx.x;
    const int b = blockIdx.y;
    const int nBase = blockIdx.x * 128;
    const int w = tid >> 6, ln = tid & 63;
    const int sr = ln >> 2, sc = (ln & 3) * 8;
    const int fr = ln & 15, q = ln >> 4;

    const ushort* gA[4];
#pragma unroll
    for (int t = 0; t < 4; t++) {
        int row = t * 64 + w * 16 + sr;
        if (row > NN - 1) row = NN - 1;   // clamp: garbage rows -> discarded C rows
        gA[t] = Mb + (size_t)b * GSTR + (size_t)row * KP + sc;
    }
    const ushort* gB[2];
#pragma unroll
    for (int t = 0; t < 2; t++) {
        int ch = nBase + t * 64 + w * 16 + sr;   // < 256, in-bounds
        gB[t] = St + (size_t)b * SSTR + (size_t)ch * NN + sc;
    }
    ushort* lA[4];
#pragma unroll
    for (int t = 0; t < 4; t++) lA[t] = &As[(t * 64 + w * 16) * 32];
    ushort* lB[2];
#pragma unroll
    for (int t = 0; t < 2; t++) lB[t] = &Bs[(t * 64 + w * 16) * 32];

    f32x4 acc[4][8];
#pragma unroll
    for (int i = 0; i < 4; i++)
#pragma unroll
        for (int j = 0; j < 8; j++) acc[i][j] = (f32x4){0.f, 0.f, 0.f, 0.f};

    const int nK = KP / 32;   // 7; B K-tail spills into next St row: * M-zero = 0
    for (int kk = 0; kk < nK; ++kk) {
        const int ko = kk * 32;
        __syncthreads();
#pragma unroll
        for (int t = 0; t < 4; t++) gl_lds16(gA[t] + ko, lA[t]);
#pragma unroll
        for (int t = 0; t < 2; t++) gl_lds16(gB[t] + ko, lB[t]);
        __syncthreads();
        bf16x8 af[4], bfr[8];
#pragma unroll
        for (int i = 0; i < 4; i++) af[i]  = *(const bf16x8*)&As[(w * 64 + i * 16 + fr) * 32 + q * 8];
#pragma unroll
        for (int j = 0; j < 8; j++) bfr[j] = *(const bf16x8*)&Bs[(j * 16 + fr) * 32 + q * 8];
#pragma unroll
        for (int i = 0; i < 4; i++)
#pragma unroll
            for (int j = 0; j < 8; j++)
                acc[i][j] = __builtin_amdgcn_mfma_f32_16x16x32_bf16(af[i], bfr[j], acc[i][j], 0, 0, 0);
    }
    ushort* Hb = H + (size_t)b * HSTR;
#pragma unroll
    for (int i = 0; i < 4; i++) {
        int node = w * 64 + i * 16 + q * 4;
#pragma unroll
        for (int j = 0; j < 8; j++) {
            int ch = nBase + j * 16 + fr;
            f32x4 v = acc[i][j];
#pragma unroll
            for (int r = 0; r < 4; r++)
                if (node + r < NN) Hb[(node + r) * HID + ch] = f2bf(v[r]);
        }
    }
}

// ---------------------------------------------------------------------------
// u = colsum(M[b]); t[o] = sum_m u[m]*H2[b][m][o]; out = t@Wp/N + pb (fp32)
__global__ __launch_bounds__(256) void finalize(
    const ushort* __restrict__ Mb, const ushort* __restrict__ H2,
    const float* __restrict__ Wp, float* __restrict__ out) {
    const int b = blockIdx.x;
    const int tid = threadIdx.x;
    __shared__ float u[NN];
    const ushort* M = Mb + (size_t)b * GSTR;
    if (tid < NN) {
        float s = 0.f;
        for (int n = 0; n < NN; ++n) s += bf2f(M[n * KP + tid]);
        u[tid] = s;
    }
    __syncthreads();
    const ushort* Hh = H2 + (size_t)b * HSTR;
    float t = 0.f;
    for (int m = 0; m < NN; ++m) t += u[m] * bf2f(Hh[m * HID + tid]);
    float p0 = t * Wp[tid * 2 + 0];
    float p1 = t * Wp[tid * 2 + 1];
#pragma unroll
    for (int off = 32; off > 0; off >>= 1) {
        p0 += __shfl_down(p0, off);
        p1 += __shfl_down(p1, off);
    }
    __shared__ float w0s[4], w1s[4];
    int wave = tid >> 6, lane = tid & 63;
    if (lane == 0) { w0s[wave] = p0; w1s[wave] = p1; }
    __syncthreads();
    if (tid == 0) {
        float a0 = w0s[0] + w0s[1] + w0s[2] + w0s[3];
        float a1 = w1s[0] + w1s[1] + w1s[2] + w1s[3];
        out[b * 2 + 0] = a0 * (1.f / NN) + Wp[512];
        out[b * 2 + 1] = a1 * (1.f / NN) + Wp[513];
    }
}

// ---------------------------------------------------------------------------
extern "C" void kernel_launch(void* const* d_in, const int* in_sizes, int n_in,
                              void* d_out, int out_size, void* d_ws, size_t ws_size,
                              hipStream_t stream) {
    const float* adj  = (const float*)d_in[0];
    const float* feat = (const float*)d_in[1];
    const float* R    = (const float*)d_in[2];
    const float* W0   = (const float*)d_in[3];
    const float* W1   = (const float*)d_in[4];
    const float* W2   = (const float*)d_in[5];
    const float* pw   = (const float*)d_in[6];
    const float* pb   = (const float*)d_in[7];

    char* ws = (char*)d_ws;
    // layout (bytes) -- total 151,072,768 (same as R3-proven usage):
    float*  Wp   = (float*)(ws);                 // 2056 (pad to 4096)
    ushort* W0t  = (ushort*)(ws + 4096);         // 114,688
    ushort* W1t  = (ushort*)(ws + 118784);       // 131,072
    ushort* Rs   = (ushort*)(ws + 249856);       // 89,600 (pad to 339,968)
    ushort* Mb   = (ushort*)(ws + 339968);       // 45,875,200 -> 46,215,168
    ushort* St   = (ushort*)(ws + 46215168);     // 52,428,800 -> 98,643,968
    ushort* H    = (ushort*)(ws + 98643968);     // 52,428,800 -> 151,072,768
    ushort* featB = H;                           // alias; dead after support-0

    prep_transpose<<<256, 256, 0, stream>>>(W0, W1, W0t, W1t);
    prep_wp<<<1, 256, 0, stream>>>(W2, pw, pb, Wp);
    prep_mask<<<(NN * KP + 255) / 256, 256, 0, stream>>>(R, Rs);
    convert_feat<<<(MTOT * 28 + 255) / 256, 256, 0, stream>>>(feat, featB);
    compute_M<<<(BATCH * 5600 + 255) / 256, 256, 0, stream>>>(adj, Rs, Mb);

    // S0^T[b] = W0t @ feat_b^T
    gemm_sup<<<1024, 256, 0, stream>>>(W0t, featB, St, KP, GSTR, KP);
    // H1 = M @ S0  (overwrites featB region, consumed above)
    gemm_prop<<<dim3(2, 512), 256, 0, stream>>>(Mb, St, H);
    // S1^T[b] = W1t @ H1_b^T
    gemm_sup<<<1024, 256, 0, stream>>>(W1t, H, St, HID, HSTR, HID);
    // H2 = M @ S1
    gemm_prop<<<dim3(2, 512), 256, 0, stream>>>(Mb, St, H);
    // out = (u^T H2) @ (W2 pw) / N + pb
    finalize<<<BATCH, 256, 0, stream>>>(Mb, H, Wp, (float*)d_out);
}

// Round 5
// 242.924 us; speedup vs baseline: 2.4011x; 1.5429x over previous
//
#include <hip/hip_runtime.h>

#define BATCH 512
#define NN    200
#define SIG1  0.73105857863f   // sigmoid(1)
#define SIG0  0.5f             // sigmoid(0)

// ---------------------------------------------------------------------------
// prep: blocks 0..156: Rs[n][m] = 0.5*(R[n][m]+R[m][n]) + (n==m)   (fp32)
//       block 157:     Wc = W0 @ (W1 @ (W2 @ pw))   [200][2] fp32
__global__ __launch_bounds__(256) void prep(
    const float* __restrict__ R,
    const float* __restrict__ W0, const float* __restrict__ W1,
    const float* __restrict__ W2, const float* __restrict__ pw,
    float* __restrict__ Rs, float* __restrict__ Wc) {
    const int blk = blockIdx.x;
    const int tid = threadIdx.x;
    if (blk < 157) {
        int idx = blk * 256 + tid;
        if (idx < NN * NN) {
            int n = idx / NN, m = idx - n * NN;
            Rs[idx] = 0.5f * (R[idx] + R[m * NN + n]) + (n == m ? 1.f : 0.f);
        }
    } else {
        __shared__ float t0[256], t1[256];
        float a0 = 0.f, a1 = 0.f;
#pragma unroll 16
        for (int c = 0; c < 256; ++c) {
            float w2 = W2[tid * 256 + c];
            a0 += w2 * pw[2 * c];
            a1 += w2 * pw[2 * c + 1];
        }
        t0[tid] = a0; t1[tid] = a1;
        __syncthreads();
        float b0 = 0.f, b1 = 0.f;
#pragma unroll 16
        for (int h = 0; h < 256; ++h) {
            float w1 = W1[tid * 256 + h];
            b0 += w1 * t0[h];
            b1 += w1 * t1[h];
        }
        __syncthreads();
        t0[tid] = b0; t1[tid] = b1;
        __syncthreads();
        if (tid < NN) {
            float c0 = 0.f, c1 = 0.f;
#pragma unroll 16
            for (int o = 0; o < 256; ++o) {
                float w0 = W0[tid * 256 + o];
                c0 += w0 * t0[o];
                c1 += w0 * t1[o];
            }
            Wc[tid * 2 + 0] = c0;
            Wc[tid * 2 + 1] = c1;
        }
    }
}

// ---------------------------------------------------------------------------
// One block per graph. Rank-1 collapsed MaskGCN:
//   u = M^T 1 ; v = M^T u ; w = M^T v ; y = X^T w ; out = (y·Wc)/N + pb
// M[n][m] = sigmoid(adj[n][m]) * Rs[n][m], adj binary -> sigmoid in {0.5, SIG1};
// thread m keeps adj column m as a 200-bit register mask (packed in phase A).
__global__ __launch_bounds__(256) void gcn_main(
    const float* __restrict__ adj, const float* __restrict__ feat,
    const float* __restrict__ Rs, const float* __restrict__ Wc,
    const float* __restrict__ pb, float* __restrict__ out) {
    const int b = blockIdx.x;
    const int tid = threadIdx.x;
    const int tcol = (tid < NN) ? tid : (NN - 1);   // clamp lanes 200..255 (results discarded)
    const float* adjb  = adj  + (size_t)b * NN * NN;
    const float* featb = feat + (size_t)b * NN * NN;
    __shared__ float xs[NN];
    __shared__ float rbuf[8];

    unsigned long long bits0 = 0, bits1 = 0, bits2 = 0, bits3 = 0;
    float u = 0.f;

    // Phase A: one pass over adj -> bit-pack column + accumulate u (fp32 exact)
#define PHASE_A(CH, BITS, NMAX)                                     \
    _Pragma("unroll 16")                                            \
    for (int j = 0; j < NMAX; ++j) {                                \
        int n = CH * 64 + j;                                        \
        float a = adjb[n * NN + tcol];                              \
        float r = Rs[n * NN + tcol];                                \
        bool bit = a > 0.5f;                                        \
        BITS |= bit ? (1ull << j) : 0ull;                           \
        u += r * (bit ? SIG1 : SIG0);                               \
    }
    PHASE_A(0, bits0, 64)
    PHASE_A(1, bits1, 64)
    PHASE_A(2, bits2, 64)
    PHASE_A(3, bits3, 8)

    if (tid < NN) xs[tid] = u;
    __syncthreads();

    // Phase B/C: v = M^T u, w = M^T v  (Rs from L2, bits from registers)
#define PHASE_MV(CH, BITS, NMAX, ACC)                               \
    _Pragma("unroll 16")                                            \
    for (int j = 0; j < NMAX; ++j) {                                \
        int n = CH * 64 + j;                                        \
        float r = Rs[n * NN + tcol];                                \
        float mv = r * (((BITS >> j) & 1ull) ? SIG1 : SIG0);        \
        ACC += mv * xs[n];                                          \
    }
    float v = 0.f;
    PHASE_MV(0, bits0, 64, v)
    PHASE_MV(1, bits1, 64, v)
    PHASE_MV(2, bits2, 64, v)
    PHASE_MV(3, bits3, 8, v)
    __syncthreads();
    if (tid < NN) xs[tid] = v;
    __syncthreads();

    float w = 0.f;
    PHASE_MV(0, bits0, 64, w)
    PHASE_MV(1, bits1, 64, w)
    PHASE_MV(2, bits2, 64, w)
    PHASE_MV(3, bits3, 8, w)
    __syncthreads();
    if (tid < NN) xs[tid] = w;
    __syncthreads();

    // Phase D: y[f] = sum_m w[m] * feat[m][f]   (one pass over feat)
    float y = 0.f;
#pragma unroll 16
    for (int m = 0; m < NN; ++m) y += xs[m] * featb[m * NN + tcol];

    // Phase E: out_j = (1/N) * sum_f y[f] * Wc[f][j] + pb[j]
    float p0 = 0.f, p1 = 0.f;
    if (tid < NN) {
        p0 = y * Wc[tid * 2 + 0];
        p1 = y * Wc[tid * 2 + 1];
    }
#pragma unroll
    for (int off = 32; off > 0; off >>= 1) {
        p0 += __shfl_down(p0, off);
        p1 += __shfl_down(p1, off);
    }
    const int wv = tid >> 6, ln = tid & 63;
    if (ln == 0) { rbuf[wv * 2] = p0; rbuf[wv * 2 + 1] = p1; }
    __syncthreads();
    if (tid == 0) {
        float r0 = rbuf[0] + rbuf[2] + rbuf[4] + rbuf[6];
        float r1 = rbuf[1] + rbuf[3] + rbuf[5] + rbuf[7];
        out[b * 2 + 0] = r0 * (1.f / NN) + pb[0];
        out[b * 2 + 1] = r1 * (1.f / NN) + pb[1];
    }
}

// ---------------------------------------------------------------------------
extern "C" void kernel_launch(void* const* d_in, const int* in_sizes, int n_in,
                              void* d_out, int out_size, void* d_ws, size_t ws_size,
                              hipStream_t stream) {
    const float* adj  = (const float*)d_in[0];
    const float* feat = (const float*)d_in[1];
    const float* R    = (const float*)d_in[2];
    const float* W0   = (const float*)d_in[3];
    const float* W1   = (const float*)d_in[4];
    const float* W2   = (const float*)d_in[5];
    const float* pw   = (const float*)d_in[6];
    const float* pb   = (const float*)d_in[7];

    char* ws = (char*)d_ws;
    float* Rs = (float*)(ws);             // 160,000 B
    float* Wc = (float*)(ws + 160000);    // 1,600 B

    prep<<<158, 256, 0, stream>>>(R, W0, W1, W2, pw, Rs, Wc);
    gcn_main<<<BATCH, 256, 0, stream>>>(adj, feat, Rs, Wc, pb, (float*)d_out);
}

// Round 6
// 230.376 us; speedup vs baseline: 2.5319x; 1.0545x over previous
//
#include <hip/hip_runtime.h>

#define BATCH 512
#define NN    200
#define QR    50               // rows per quarter-slice
#define SIG1  0.73105857863f   // sigmoid(1)
#define SIG0  0.5f             // sigmoid(0)

// ---------------------------------------------------------------------------
// prep: blocks 0..156: Rs[n][m] = 0.5*(R[n][m]+R[m][n]) + (n==m)   (fp32)
//       block 157:     Wc = W0 @ (W1 @ (W2 @ pw))   [200][2] fp32
__global__ __launch_bounds__(256) void prep(
    const float* __restrict__ R,
    const float* __restrict__ W0, const float* __restrict__ W1,
    const float* __restrict__ W2, const float* __restrict__ pw,
    float* __restrict__ Rs, float* __restrict__ Wc) {
    const int blk = blockIdx.x;
    const int tid = threadIdx.x;
    if (blk < 157) {
        int idx = blk * 256 + tid;
        if (idx < NN * NN) {
            int n = idx / NN, m = idx - n * NN;
            Rs[idx] = 0.5f * (R[idx] + R[m * NN + n]) + (n == m ? 1.f : 0.f);
        }
    } else {
        __shared__ float t0[256], t1[256];
        float a0 = 0.f, a1 = 0.f;
#pragma unroll 16
        for (int c = 0; c < 256; ++c) {
            float w2 = W2[tid * 256 + c];
            a0 += w2 * pw[2 * c];
            a1 += w2 * pw[2 * c + 1];
        }
        t0[tid] = a0; t1[tid] = a1;
        __syncthreads();
        float b0 = 0.f, b1 = 0.f;
#pragma unroll 16
        for (int h = 0; h < 256; ++h) {
            float w1 = W1[tid * 256 + h];
            b0 += w1 * t0[h];
            b1 += w1 * t1[h];
        }
        __syncthreads();
        t0[tid] = b0; t1[tid] = b1;
        __syncthreads();
        if (tid < NN) {
            float c0 = 0.f, c1 = 0.f;
#pragma unroll 16
            for (int o = 0; o < 256; ++o) {
                float w0 = W0[tid * 256 + o];
                c0 += w0 * t0[o];
                c1 += w0 * t1[o];
            }
            Wc[tid * 2 + 0] = c0;
            Wc[tid * 2 + 1] = c1;
        }
    }
}

// ---------------------------------------------------------------------------
// One 1024-thread block per graph. Rank-1 collapsed MaskGCN:
//   u = M^T 1 ; v = M^T u ; w = M^T v ; y = X^T w ; out = (y·Wc)/N + pb
// Thread (q = tid>>8, col = tid&255): 50-row slice of column col.
// adj binary -> sigmoid in {SIG0, SIG1}; 50-bit register mask packed in phase A.
__global__ __launch_bounds__(1024) void gcn_main(
    const float* __restrict__ adj, const float* __restrict__ feat,
    const float* __restrict__ Rs, const float* __restrict__ Wc,
    const float* __restrict__ pb, float* __restrict__ out) {
    const int b = blockIdx.x;
    const int tid = threadIdx.x;
    const int col = tid & 255;
    const int q = tid >> 8;                        // 0..3
    const int tcol = (col < NN) ? col : (NN - 1);  // clamp; clamped results discarded
    const int n0 = q * QR;
    const float* adjb  = adj  + (size_t)b * NN * NN;
    const float* featb = feat + (size_t)b * NN * NN;
    __shared__ float us[1024];
    __shared__ float xs[NN];
    __shared__ float rbuf[32];

    // Phase A: one pass over the adj slice -> bit-pack + partial u
    unsigned long long bits = 0;
    float u = 0.f;
#pragma unroll 10
    for (int j = 0; j < QR; ++j) {
        int n = n0 + j;
        float a = adjb[n * NN + tcol];
        float r = Rs[n * NN + tcol];
        bool bit = a > 0.5f;
        bits |= bit ? (1ull << j) : 0ull;
        u += r * (bit ? SIG1 : SIG0);
    }
    us[tid] = u;
    __syncthreads();
    if (tid < NN) xs[tid] = us[tid] + us[256 + tid] + us[512 + tid] + us[768 + tid];
    __syncthreads();

    // Phase B: v = M^T u   (Rs from L2, bits from registers, xs broadcast)
    float v = 0.f;
#pragma unroll 10
    for (int j = 0; j < QR; ++j) {
        int n = n0 + j;
        float r = Rs[n * NN + tcol];
        v += r * (((bits >> j) & 1ull) ? SIG1 : SIG0) * xs[n];
    }
    us[tid] = v;
    __syncthreads();   // all phase-B reads of xs done
    if (tid < NN) xs[tid] = us[tid] + us[256 + tid] + us[512 + tid] + us[768 + tid];
    __syncthreads();

    // Phase C: w = M^T v
    float w = 0.f;
#pragma unroll 10
    for (int j = 0; j < QR; ++j) {
        int n = n0 + j;
        float r = Rs[n * NN + tcol];
        w += r * (((bits >> j) & 1ull) ? SIG1 : SIG0) * xs[n];
    }
    us[tid] = w;
    __syncthreads();
    if (tid < NN) xs[tid] = us[tid] + us[256 + tid] + us[512 + tid] + us[768 + tid];
    __syncthreads();

    // Phase D: partial y[col] over this quarter's feat rows; fold into y·Wc
    float y = 0.f;
#pragma unroll 10
    for (int j = 0; j < QR; ++j) {
        int m = n0 + j;
        y += xs[m] * featb[m * NN + tcol];
    }
    float p0 = 0.f, p1 = 0.f;
    if (col < NN) {
        p0 = y * Wc[col * 2 + 0];
        p1 = y * Wc[col * 2 + 1];
    }
#pragma unroll
    for (int off = 32; off > 0; off >>= 1) {
        p0 += __shfl_down(p0, off);
        p1 += __shfl_down(p1, off);
    }
    const int wv = tid >> 6, ln = tid & 63;
    if (ln == 0) { rbuf[wv * 2] = p0; rbuf[wv * 2 + 1] = p1; }
    __syncthreads();
    if (tid == 0) {
        float r0 = 0.f, r1 = 0.f;
#pragma unroll
        for (int i = 0; i < 16; ++i) { r0 += rbuf[i * 2]; r1 += rbuf[i * 2 + 1]; }
        out[b * 2 + 0] = r0 * (1.f / NN) + pb[0];
        out[b * 2 + 1] = r1 * (1.f / NN) + pb[1];
    }
}

// ---------------------------------------------------------------------------
extern "C" void kernel_launch(void* const* d_in, const int* in_sizes, int n_in,
                              void* d_out, int out_size, void* d_ws, size_t ws_size,
                              hipStream_t stream) {
    const float* adj  = (const float*)d_in[0];
    const float* feat = (const float*)d_in[1];
    const float* R    = (const float*)d_in[2];
    const float* W0   = (const float*)d_in[3];
    const float* W1   = (const float*)d_in[4];
    const float* W2   = (const float*)d_in[5];
    const float* pw   = (const float*)d_in[6];
    const float* pb   = (const float*)d_in[7];

    char* ws = (char*)d_ws;
    float* Rs = (float*)(ws);             // 160,000 B
    float* Wc = (float*)(ws + 160000);    // 1,600 B

    prep<<<158, 256, 0, stream>>>(R, W0, W1, W2, pw, Rs, Wc);
    gcn_main<<<BATCH, 1024, 0, stream>>>(adj, feat, Rs, Wc, pb, (float*)d_out);
}

// Round 7
// 228.107 us; speedup vs baseline: 2.5571x; 1.0099x over previous
//
#include <hip/hip_runtime.h>

#define BATCH 512
#define NN    200
#define SIG1  0.73105857863f   // sigmoid(1)
#define SIG0  0.5f             // sigmoid(0)

// ---------------------------------------------------------------------------
// prep: blocks 0..156: Rs[n][m] = 0.5*(R[n][m]+R[m][n]) + (n==m)   (fp32)
//       block 157:     Wc = W0 @ (W1 @ (W2 @ pw))   [200][2] fp32
__global__ __launch_bounds__(256) void prep(
    const float* __restrict__ R,
    const float* __restrict__ W0, const float* __restrict__ W1,
    const float* __restrict__ W2, const float* __restrict__ pw,
    float* __restrict__ Rs, float* __restrict__ Wc) {
    const int blk = blockIdx.x;
    const int tid = threadIdx.x;
    if (blk < 157) {
        int idx = blk * 256 + tid;
        if (idx < NN * NN) {
            int n = idx / NN, m = idx - n * NN;
            Rs[idx] = 0.5f * (R[idx] + R[m * NN + n]) + (n == m ? 1.f : 0.f);
        }
    } else {
        __shared__ float t0[256], t1[256];
        float a0 = 0.f, a1 = 0.f;
#pragma unroll 16
        for (int c = 0; c < 256; ++c) {
            float w2 = W2[tid * 256 + c];
            a0 += w2 * pw[2 * c];
            a1 += w2 * pw[2 * c + 1];
        }
        t0[tid] = a0; t1[tid] = a1;
        __syncthreads();
        float b0 = 0.f, b1 = 0.f;
#pragma unroll 16
        for (int h = 0; h < 256; ++h) {
            float w1 = W1[tid * 256 + h];
            b0 += w1 * t0[h];
            b1 += w1 * t1[h];
        }
        __syncthreads();
        t0[tid] = b0; t1[tid] = b1;
        __syncthreads();
        if (tid < NN) {
            float c0 = 0.f, c1 = 0.f;
#pragma unroll 16
            for (int o = 0; o < 256; ++o) {
                float w0 = W0[tid * 256 + o];
                c0 += w0 * t0[o];
                c1 += w0 * t1[o];
            }
            Wc[tid * 2 + 0] = c0;
            Wc[tid * 2 + 1] = c1;
        }
    }
}

// ---------------------------------------------------------------------------
// One 1024-thread block per graph. Rank-1 collapsed MaskGCN, float4 passes:
//   u = M^T 1 ; v = M^T u ; w = M^T v ; y = X^T w ; out = (y·Wc)/N + pb
// Thread (q = tid>>6, c4 = tid&63): rows r0..r0+nr (12/13, wave-uniform),
// cols [4*c4, 4*c4+4) (c4 clamped to 49; duplicate results discarded).
// adj binary -> sigmoid in {SIG0, SIG1}; per-col row-slice bitmask in uint.
__global__ __launch_bounds__(1024) void gcn_main(
    const float* __restrict__ adj, const float* __restrict__ feat,
    const float* __restrict__ Rs, const float* __restrict__ Wc,
    const float* __restrict__ pb, float* __restrict__ out) {
    const int b = blockIdx.x;
    const int tid = threadIdx.x;
    const int c4 = tid & 63;
    const int q  = tid >> 6;                       // 0..15, wave-uniform
    const int cc = (c4 < 50) ? c4 : 49;            // clamp (dup results discarded)
    const int col0 = cc * 4;
    const int r0 = (q < 8) ? 13 * q : 104 + 12 * (q - 8);
    const int nr = (q < 8) ? 13 : 12;              // wave-uniform trip count
    const float* adjb  = adj  + (size_t)b * NN * NN;
    const float* featb = feat + (size_t)b * NN * NN;
    __shared__ float4 us[1024];
    __shared__ float xs[NN];

    // Phase A: one float4 pass over adj slice -> bitmasks + partial u
    uint m0 = 0, m1 = 0, m2 = 0, m3 = 0;
    float4 acc = {0.f, 0.f, 0.f, 0.f};
#pragma unroll 4
    for (int j = 0; j < nr; ++j) {
        int n = r0 + j;
        float4 a = *(const float4*)(adjb + n * NN + col0);
        float4 r = *(const float4*)(Rs   + n * NN + col0);
        bool t;
        t = a.x > 0.5f; m0 |= (uint)t << j; acc.x += r.x * (t ? SIG1 : SIG0);
        t = a.y > 0.5f; m1 |= (uint)t << j; acc.y += r.y * (t ? SIG1 : SIG0);
        t = a.z > 0.5f; m2 |= (uint)t << j; acc.z += r.z * (t ? SIG1 : SIG0);
        t = a.w > 0.5f; m3 |= (uint)t << j; acc.w += r.w * (t ? SIG1 : SIG0);
    }
    us[tid] = acc;
    __syncthreads();
    if (tid < 64) {
        float4 s = us[tid];
#pragma unroll
        for (int qq = 1; qq < 16; ++qq) {
            float4 p = us[qq * 64 + tid];
            s.x += p.x; s.y += p.y; s.z += p.z; s.w += p.w;
        }
        if (tid < 50) {
            xs[tid * 4 + 0] = s.x; xs[tid * 4 + 1] = s.y;
            xs[tid * 4 + 2] = s.z; xs[tid * 4 + 3] = s.w;
        }
    }
    __syncthreads();

    // Phase B: v = M^T u  (Rs from L2, masks in regs, xs broadcast from LDS)
    acc = (float4){0.f, 0.f, 0.f, 0.f};
#pragma unroll 4
    for (int j = 0; j < nr; ++j) {
        int n = r0 + j;
        float4 r = *(const float4*)(Rs + n * NN + col0);
        float xn = xs[n];
        acc.x += r.x * (((m0 >> j) & 1u) ? SIG1 : SIG0) * xn;
        acc.y += r.y * (((m1 >> j) & 1u) ? SIG1 : SIG0) * xn;
        acc.z += r.z * (((m2 >> j) & 1u) ? SIG1 : SIG0) * xn;
        acc.w += r.w * (((m3 >> j) & 1u) ? SIG1 : SIG0) * xn;
    }
    us[tid] = acc;
    __syncthreads();
    if (tid < 64) {
        float4 s = us[tid];
#pragma unroll
        for (int qq = 1; qq < 16; ++qq) {
            float4 p = us[qq * 64 + tid];
            s.x += p.x; s.y += p.y; s.z += p.z; s.w += p.w;
        }
        if (tid < 50) {
            xs[tid * 4 + 0] = s.x; xs[tid * 4 + 1] = s.y;
            xs[tid * 4 + 2] = s.z; xs[tid * 4 + 3] = s.w;
        }
    }
    __syncthreads();

    // Phase C: w = M^T v
    acc = (float4){0.f, 0.f, 0.f, 0.f};
#pragma unroll 4
    for (int j = 0; j < nr; ++j) {
        int n = r0 + j;
        float4 r = *(const float4*)(Rs + n * NN + col0);
        float xn = xs[n];
        acc.x += r.x * (((m0 >> j) & 1u) ? SIG1 : SIG0) * xn;
        acc.y += r.y * (((m1 >> j) & 1u) ? SIG1 : SIG0) * xn;
        acc.z += r.z * (((m2 >> j) & 1u) ? SIG1 : SIG0) * xn;
        acc.w += r.w * (((m3 >> j) & 1u) ? SIG1 : SIG0) * xn;
    }
    us[tid] = acc;
    __syncthreads();
    if (tid < 64) {
        float4 s = us[tid];
#pragma unroll
        for (int qq = 1; qq < 16; ++qq) {
            float4 p = us[qq * 64 + tid];
            s.x += p.x; s.y += p.y; s.z += p.z; s.w += p.w;
        }
        if (tid < 50) {
            xs[tid * 4 + 0] = s.x; xs[tid * 4 + 1] = s.y;
            xs[tid * 4 + 2] = s.z; xs[tid * 4 + 3] = s.w;
        }
    }
    __syncthreads();

    // Phase D: partial y over this slice's feat rows
    acc = (float4){0.f, 0.f, 0.f, 0.f};
#pragma unroll 4
    for (int j = 0; j < nr; ++j) {
        int n = r0 + j;
        float4 f = *(const float4*)(featb + n * NN + col0);
        float xn = xs[n];
        acc.x += f.x * xn; acc.y += f.y * xn;
        acc.z += f.z * xn; acc.w += f.w * xn;
    }
    us[tid] = acc;
    __syncthreads();

    // Phase E: wave 0 combines y, dots with Wc, reduces, writes out
    if (tid < 64) {
        float4 s = us[tid];
#pragma unroll
        for (int qq = 1; qq < 16; ++qq) {
            float4 p = us[qq * 64 + tid];
            s.x += p.x; s.y += p.y; s.z += p.z; s.w += p.w;
        }
        float p0 = 0.f, p1 = 0.f;
        if (tid < 50) {
            int c0i = tid * 4;
            p0 = s.x * Wc[(c0i + 0) * 2] + s.y * Wc[(c0i + 1) * 2]
               + s.z * Wc[(c0i + 2) * 2] + s.w * Wc[(c0i + 3) * 2];
            p1 = s.x * Wc[(c0i + 0) * 2 + 1] + s.y * Wc[(c0i + 1) * 2 + 1]
               + s.z * Wc[(c0i + 2) * 2 + 1] + s.w * Wc[(c0i + 3) * 2 + 1];
        }
#pragma unroll
        for (int off = 32; off > 0; off >>= 1) {
            p0 += __shfl_down(p0, off);
            p1 += __shfl_down(p1, off);
        }
        if (tid == 0) {
            out[b * 2 + 0] = p0 * (1.f / NN) + pb[0];
            out[b * 2 + 1] = p1 * (1.f / NN) + pb[1];
        }
    }
}

// ---------------------------------------------------------------------------
extern "C" void kernel_launch(void* const* d_in, const int* in_sizes, int n_in,
                              void* d_out, int out_size, void* d_ws, size_t ws_size,
                              hipStream_t stream) {
    const float* adj  = (const float*)d_in[0];
    const float* feat = (const float*)d_in[1];
    const float* R    = (const float*)d_in[2];
    const float* W0   = (const float*)d_in[3];
    const float* W1   = (const float*)d_in[4];
    const float* W2   = (const float*)d_in[5];
    const float* pw   = (const float*)d_in[6];
    const float* pb   = (const float*)d_in[7];

    char* ws = (char*)d_ws;
    float* Rs = (float*)(ws);             // 160,000 B
    float* Wc = (float*)(ws + 160000);    // 1,600 B

    prep<<<158, 256, 0, stream>>>(R, W0, W1, W2, pw, Rs, Wc);
    gcn_main<<<BATCH, 1024, 0, stream>>>(adj, feat, Rs, Wc, pb, (float*)d_out);
}